// Round 8
// baseline (223.419 us; speedup 1.0000x reference)
//
#include <hip/hip_runtime.h>
#include <stdint.h>

#define NPTS 2048
#define MAGIC 0x5A5A5A5Au

// ---- workspace layout (bytes) ----
// Bp fragment-ordered: [z][qb=16][s=64][frag 1KB]; frag slot L holds
// (q-col n=L>>2, k-range (L&3)*8..+8). Reader lane (quad,n) -> offset n*64+quad*16.
#define BP_OFF    0ULL
#define BP_BYTES  (8ULL * 16 * 64 * 1024)      // 8 MB
#define W2F_OFF   (BP_OFF + BP_BYTES)
#define W2F_BYTES (24ULL * 1024)
#define WXF_OFF   (W2F_OFF + W2F_BYTES)
#define WXF_BYTES (24ULL * 1024)
#define FLAG_OFF  (WXF_OFF + WXF_BYTES)        // 256 bp flags + 2 weight flags

typedef __attribute__((ext_vector_type(8))) short bf16x8;
typedef __attribute__((ext_vector_type(4))) float f32x4;
typedef __attribute__((ext_vector_type(4))) unsigned int u32x4;

__device__ __forceinline__ unsigned f2bf(float f) {
  union { float f; unsigned u; } v; v.f = f;
  return (v.u + 0x7FFFu + ((v.u >> 16) & 1u)) >> 16;  // RNE
}

__device__ __forceinline__ bf16x8 pack8(const float4 a, const float4 b) {
  u32x4 r;
  r[0] = f2bf(a.x) | (f2bf(a.y) << 16);
  r[1] = f2bf(a.z) | (f2bf(a.w) << 16);
  r[2] = f2bf(b.x) | (f2bf(b.y) << 16);
  r[3] = f2bf(b.z) | (f2bf(b.w) << 16);
  union { u32x4 u; bf16x8 h; } c; c.u = r; return c.h;
}

// ======== single fused kernel: produce Bp slice -> flag -> masks -> GEMM -> out ========
// grid 256 = (z = bx&7, at = bx>>3: 64 a-rows). 1024 thr = 16 waves = 4/SIMD.
// K-loop wave (rw = w&3, ch = (w>>2)&1, kh = w>>3): rows 16rw..+16, col-frags 8ch..+8,
// k-steps kh*32..+32. 1 mask unpack : 8 MFMAs. LDS 104 KB -> 1 block/CU (all resident).
__global__ __launch_bounds__(1024, 4)
void fused(const float* __restrict__ feat, const float* __restrict__ geom,
           const float* __restrict__ Wk, unsigned char* __restrict__ ws,
           float* __restrict__ out) {
  __shared__ __align__(16) float glds[NPTS * 3];   // 24 KB, live whole kernel
  __shared__ unsigned int Mw[64 * 64];             // 16 KB mask bits
  __shared__ __align__(16) float Ct[64 * 256];     // 64 KB: phase A = FT(stride 68); epilogue = C

  const int t = threadIdx.x, lane = t & 63, w = t >> 6;   // w = 0..15
  const int quad = lane >> 4, n = lane & 15;
  const int bx = blockIdx.x;
  const int z = bx & 7, at = bx >> 3, a0 = at * 64;
  const int fragoff = n * 64 + quad * 16;
  unsigned int* flags = (unsigned int*)(ws + FLAG_OFF);

  // ---- geometry of this z into LDS ----
  const float* gz = geom + (size_t)z * NPTS * 3;
#pragma unroll
  for (int i = 0; i < 2; ++i) {
    const int idx = i * 1024 + t;
    if (idx < 1536) ((float4*)glds)[idx] = ((const float4*)gz)[idx];
  }
  __syncthreads();

  // ---- weight fragments (blocks 0 and 1 only) ----
  if (bx == 0) {
    for (int e = t; e < 1536; e += 1024) {   // W2F: lane holds W2[k=kb*32+qd*8+jj][i=cb*16+nn]
      const int frag = e >> 6, lp = e & 63, nn = lp >> 2, qd = lp & 3;
      const int kb = frag >> 2, cb = frag & 3;
      u32x4 pv;
#pragma unroll
      for (int p = 0; p < 4; ++p) {
        const int k0 = kb * 32 + qd * 8 + 2 * p;
        const float v0 = Wk[(k0 >> 6) * 4096 + (cb * 16 + nn) * 64 + (k0 & 63)];
        const float v1 = Wk[((k0 + 1) >> 6) * 4096 + (cb * 16 + nn) * 64 + ((k0 + 1) & 63)];
        pv[p] = f2bf(v0) | (f2bf(v1) << 16);
      }
      *(u32x4*)(ws + W2F_OFF + (size_t)frag * 1024 + lp * 16) = pv;
    }
  } else if (bx == 1) {
    for (int e = t; e < 1536; e += 1024) {   // WXF: lane holds Wk[xi>>6][xi&63][k...], xi=cb*16+nn
      const int frag = e >> 6, lp = e & 63, nn = lp >> 2, qd = lp & 3;
      const int kb = frag / 12, cb = frag % 12, xi = cb * 16 + nn;
      u32x4 pv;
#pragma unroll
      for (int p = 0; p < 4; ++p) {
        const int k0 = kb * 32 + qd * 8 + 2 * p;
        const float v0 = Wk[(xi >> 6) * 4096 + (xi & 63) * 64 + k0];
        const float v1 = Wk[(xi >> 6) * 4096 + (xi & 63) * 64 + k0 + 1];
        pv[p] = f2bf(v0) | (f2bf(v1) << 16);
      }
      *(u32x4*)(ws + WXF_OFF + (size_t)frag * 1024 + lp * 16) = pv;
    }
  }

  // ---- phase A: produce this block's Bp slice (s = 2at, 2at+1) ----
  {
    float* FT = Ct;                              // FT[j][k] stride 68 (16B-aligned rows)
    const float* fz = feat + ((size_t)z * NPTS + at * 64) * 64;
    {
      const int row = t >> 4, c4 = (t & 15) << 2;
      const float4 v = *(const float4*)&fz[row * 64 + c4];
      FT[(c4 + 0) * 68 + row] = v.x; FT[(c4 + 1) * 68 + row] = v.y;
      FT[(c4 + 2) * 68 + row] = v.z; FT[(c4 + 3) * 68 + row] = v.w;
    }
    __syncthreads();
    // wave w: s-chunk sc = w>>3, u = w&7 -> frags qb = u and u+8 (j identical for both)
    const int u = w & 7, sc = w >> 3;
    const int L = lane, nn = L >> 2, k0 = (L & 3) * 8;
    const int j = (u & 3) * 16 + nn;
    float f[8];
#pragma unroll
    for (int i = 0; i < 8; ++i) f[i] = FT[j * 68 + sc * 32 + k0 + i];
    const int gb = (at * 64 + sc * 32 + k0) * 3;
#pragma unroll
    for (int half = 0; half < 2; ++half) {
      const int qb = u + half * 8, x = qb >> 2;  // x = 0..3 (3 => plain F)
      u32x4 pv;
#pragma unroll
      for (int p = 0; p < 4; ++p) {
        float f0 = f[2 * p], f1 = f[2 * p + 1];
        if (x < 3) { f0 *= glds[gb + 6 * p + x]; f1 *= glds[gb + 6 * p + 3 + x]; }
        pv[p] = f2bf(f0) | (f2bf(f1) << 16);
      }
      *(u32x4*)(ws + BP_OFF + (size_t)z * 1048576 + (size_t)qb * 65536 +
                (size_t)(at * 2 + sc) * 1024 + L * 16) = pv;
    }
  }
  __threadfence();       // make our global stores agent-visible
  __syncthreads();
  if (t == 0)
    __hip_atomic_store(&flags[z * 32 + at], MAGIC, __ATOMIC_RELEASE, __HIP_MEMORY_SCOPE_AGENT);
  if (bx == 0 && t == 1)
    __hip_atomic_store(&flags[256], MAGIC, __ATOMIC_RELEASE, __HIP_MEMORY_SCOPE_AGENT);
  if (bx == 1 && t == 1)
    __hip_atomic_store(&flags[257], MAGIC, __ATOMIC_RELEASE, __HIP_MEMORY_SCOPE_AGENT);

  // ---- mask bit precompute (overlaps other blocks' produce) ----
  {
    const int mr = t & 63, sg = t >> 6;
    const float pa0 = glds[(a0 + mr) * 3 + 0];
    const float pa1 = glds[(a0 + mr) * 3 + 1];
    const float pa2 = glds[(a0 + mr) * 3 + 2];
#pragma unroll
    for (int si = 0; si < 4; ++si) {
      const int s = sg * 4 + si;
      unsigned bits = 0;
#pragma unroll
      for (int k8 = 0; k8 < 4; ++k8) {
        float v[24];
#pragma unroll
        for (int i = 0; i < 6; ++i)
          *(float4*)&v[i * 4] = *(const float4*)&glds[s * 96 + k8 * 24 + i * 4];
#pragma unroll
        for (int p = 0; p < 8; ++p) {
          const float d0 = v[p * 3 + 0] - pa0;
          const float d1 = v[p * 3 + 1] - pa1;
          const float d2 = v[p * 3 + 2] - pa2;
          const float n2 = fmaf(d2, d2, fmaf(d1, d1, d0 * d0));
          bits |= (n2 < 1.0f ? 1u : 0u) << (k8 * 8 + p);
        }
      }
      Mw[s * 64 + mr] = bits;
    }
  }

  // ---- wait for all producers of this z (+ weight frags) ----
  if (t < 32)
    while (__hip_atomic_load(&flags[z * 32 + t], __ATOMIC_ACQUIRE, __HIP_MEMORY_SCOPE_AGENT) != MAGIC)
      __builtin_amdgcn_s_sleep(8);
  if (t == 32 || t == 33)
    while (__hip_atomic_load(&flags[256 + (t - 32)], __ATOMIC_ACQUIRE, __HIP_MEMORY_SCOPE_AGENT) != MAGIC)
      __builtin_amdgcn_s_sleep(8);
  __syncthreads();       // Mw complete + Bp visible; no more barriers until epilogue

  // ---- K-loop: wave (rw, ch, kh); 32 steps; 1 unpack : 8 MFMAs ----
  const int rw = w & 3, ch = (w >> 2) & 1, kh = w >> 3;
  const int rbase = rw * 16, qsh = quad * 8;
  const unsigned char* bw = ws + BP_OFF + (size_t)z * 1048576 +
                            (size_t)(ch * 8) * 65536 + (size_t)kh * 32768 + fragoff;

  f32x4 acc[8];
#pragma unroll
  for (int cb = 0; cb < 8; ++cb)
#pragma unroll
    for (int r = 0; r < 4; ++r) acc[cb][r] = 0.f;

  bf16x8 Bf0[8], Bf1[8];
#pragma unroll
  for (int cb = 0; cb < 8; ++cb) {
    Bf0[cb] = *(const bf16x8*)(bw + (size_t)cb * 65536 + 0 * 1024);
    Bf1[cb] = *(const bf16x8*)(bw + (size_t)cb * 65536 + 1 * 1024);
  }

#define BSTEP(SS, BB)                                                          \
  {                                                                            \
    const unsigned mq = (Mw[((SS) + kh * 32) * 64 + rbase + n] >> qsh) & 0xFFu;\
    u32x4 aw;                                                                  \
    aw[0] = (mq & 1u)   * 0x3F80u | (mq & 2u)   * 0x1FC00000u;                 \
    aw[1] = (mq & 4u)   * 0x0FE0u | (mq & 8u)   * 0x07F00000u;                 \
    aw[2] = (mq & 16u)  * 0x03F8u | (mq & 32u)  * 0x01FC0000u;                 \
    aw[3] = (mq & 64u)  * 0xFEu   | (mq & 128u) * 0x007F0000u;                 \
    union { u32x4 u; bf16x8 h; } cv; cv.u = aw;                                \
    _Pragma("unroll") for (int cb = 0; cb < 8; ++cb)                           \
      acc[cb] = __builtin_amdgcn_mfma_f32_16x16x32_bf16(cv.h, BB[cb],          \
                                                        acc[cb], 0, 0, 0);     \
    const int sp = (SS) + 2 > 31 ? 31 : (SS) + 2;                              \
    _Pragma("unroll") for (int cb = 0; cb < 8; ++cb)                           \
      BB[cb] = *(const bf16x8*)(bw + (size_t)cb * 65536 + (size_t)sp * 1024);  \
  }

  for (int s2 = 0; s2 < 32; s2 += 2) {
    BSTEP(s2, Bf0)
    BSTEP(s2 + 1, Bf1)
  }
#undef BSTEP

  // ---- epilogue: kh=0 writes Ct, kh=1 adds, then transpose + weight GEMM ----
  if (kh == 0) {
#pragma unroll
    for (int cb = 0; cb < 8; ++cb)
#pragma unroll
      for (int r = 0; r < 4; ++r) {
        const int row = rbase + quad * 4 + r;          // C/D: row = quad*4+r
        const int col = (ch * 8 + cb) * 16 + n;        // C/D: col = n
        Ct[row * 256 + (((col >> 2) ^ row) << 2) + (col & 3)] = acc[cb][r];
      }
  }
  __syncthreads();
  if (kh == 1) {
#pragma unroll
    for (int cb = 0; cb < 8; ++cb)
#pragma unroll
      for (int r = 0; r < 4; ++r) {
        const int row = rbase + quad * 4 + r;
        const int col = (ch * 8 + cb) * 16 + n;
        Ct[row * 256 + (((col >> 2) ^ row) << 2) + (col & 3)] += acc[cb][r];
      }
  }
  __syncthreads();

  if (w < 4) {
    const int lm = 16 * w + n;                         // final-GEMM A row
    bf16x8 Across[8];
#pragma unroll
    for (int kb = 0; kb < 8; ++kb) {
      const int c0 = (kb * 8 + quad * 2) ^ lm;
      const int c1 = (kb * 8 + quad * 2 + 1) ^ lm;
      const float4 f0 = *(const float4*)&Ct[lm * 256 + c0 * 4];
      const float4 f1 = *(const float4*)&Ct[lm * 256 + c1 * 4];
      Across[kb] = pack8(f0, f1);
    }

    f32x4 mn[4], V[12];
#pragma unroll
    for (int i = 0; i < 4; ++i)
#pragma unroll
      for (int r = 0; r < 4; ++r) mn[i][r] = 0.f;
#pragma unroll
    for (int i = 0; i < 12; ++i)
#pragma unroll
      for (int r = 0; r < 4; ++r) V[i][r] = 0.f;

    const unsigned char* w2f = ws + W2F_OFF;
    const unsigned char* wxf = ws + WXF_OFF;
#pragma unroll
    for (int kb = 0; kb < 6; ++kb)
#pragma unroll
      for (int cb = 0; cb < 4; ++cb) {
        const bf16x8 Bfr = *(const bf16x8*)(w2f + (size_t)(kb * 4 + cb) * 1024 + fragoff);
        mn[cb] = __builtin_amdgcn_mfma_f32_16x16x32_bf16(Across[kb], Bfr, mn[cb], 0, 0, 0);
      }
#pragma unroll
    for (int kb = 0; kb < 2; ++kb)
#pragma unroll
      for (int cb = 0; cb < 12; ++cb) {
        const bf16x8 Bfr = *(const bf16x8*)(wxf + (size_t)(kb * 12 + cb) * 1024 + fragoff);
        V[cb] = __builtin_amdgcn_mfma_f32_16x16x32_bf16(Across[6 + kb], Bfr, V[cb], 0, 0, 0);
      }

#pragma unroll
    for (int r = 0; r < 4; ++r) {
      const int af = a0 + 16 * w + quad * 4 + r;       // C/D row = quad*4 + r
      const float g0 = glds[af * 3 + 0], g1 = glds[af * 3 + 1], g2 = glds[af * 3 + 2];
#pragma unroll
      for (int cb = 0; cb < 4; ++cb) {
        const float v = mn[cb][r] - g0 * V[cb][r] - g1 * V[cb + 4][r] - g2 * V[cb + 8][r];
        out[((size_t)z * NPTS + af) * 64 + cb * 16 + n] = v;
      }
    }
  }
}

extern "C" void kernel_launch(void* const* d_in, const int* in_sizes, int n_in,
                              void* d_out, int out_size, void* d_ws, size_t ws_size,
                              hipStream_t stream) {
  const float* feat = (const float*)d_in[0];  // [8,2048,64]
  const float* geom = (const float*)d_in[1];  // [8,2048,3]
  const float* Wk   = (const float*)d_in[2];  // [3,64,64]
  float* out = (float*)d_out;                 // [8,2048,64] fp32
  unsigned char* ws = (unsigned char*)d_ws;   // ~8.5 MB used

  fused<<<dim3(256), 1024, 0, stream>>>(feat, geom, Wk, ws, out);
}

// Round 9
// 108.587 us; speedup vs baseline: 2.0575x; 2.0575x over previous
//
#include <hip/hip_runtime.h>
#include <stdint.h>

#define NPTS 2048

// ---- workspace layout (bytes) ----
// Bp fragment-ordered (R4-verified): [z][qb=16][s=64][frag 1KB]; frag slot L holds
// (q-col n=L>>2, k-range (L&3)*8..+8). Reader lane (quad,n) -> offset n*64+quad*16.
#define BP_OFF    0ULL
#define BP_BYTES  (8ULL * 16 * 64 * 1024)      // 8 MB
#define W2F_OFF   (BP_OFF + BP_BYTES)
#define W2F_BYTES (24ULL * 1024)               // frags kb0..5 x cb0..3
#define WXF_OFF   (W2F_OFF + W2F_BYTES)
#define WXF_BYTES (24ULL * 1024)               // frags kb0..1 x cb0..11
// Mask words: [z][at=32][kw=64][64 dwords]; dword (r&15)*4+(r>>4)&3 = row r's kw word.
#define MW_OFF    (WXF_OFF + WXF_BYTES)
#define MW_BYTES  (8ULL * 32 * 64 * 256)       // 4 MB  (total ~12.4 MB)

typedef __attribute__((ext_vector_type(8))) short bf16x8;
typedef __attribute__((ext_vector_type(4))) float f32x4;
typedef __attribute__((ext_vector_type(4))) unsigned int u32x4;

__device__ __forceinline__ unsigned f2bf(float f) {
  union { float f; unsigned u; } v; v.f = f;
  return (v.u + 0x7FFFu + ((v.u >> 16) & 1u)) >> 16;  // RNE
}

// 8 mask bits -> 8 bf16 (1.0/0.0): bit-deposit mul + v_perm + mul. ~16 ops.
__device__ __forceinline__ bf16x8 unpack_mask(unsigned mq) {
  const unsigned dep0 = ((mq & 15u) * 0x204081u) & 0x01010101u;        // bits0-3 -> bytes
  const unsigned dep1 = (((mq >> 4) & 15u) * 0x204081u) & 0x01010101u; // bits4-7
  u32x4 aw;
  aw[0] = __builtin_amdgcn_perm(dep0, 0u, 0x0C050C04u) * 0x3F80u;
  aw[1] = __builtin_amdgcn_perm(dep0, 0u, 0x0C070C06u) * 0x3F80u;
  aw[2] = __builtin_amdgcn_perm(dep1, 0u, 0x0C050C04u) * 0x3F80u;
  aw[3] = __builtin_amdgcn_perm(dep1, 0u, 0x0C070C06u) * 0x3F80u;
  union { u32x4 u; bf16x8 h; } cv; cv.u = aw;
  return cv.h;
}

// ========== K1: Bp frags (R4-verbatim) + weight frags + mask bitwords ==========
__global__ __launch_bounds__(256, 2) void k1_prep(const float* __restrict__ feat,
                                                  const float* __restrict__ geom,
                                                  const float* __restrict__ Wk,
                                                  unsigned char* __restrict__ ws) {
  const int blk = blockIdx.x, t = threadIdx.x;
  if (blk < 512) {
    const int z = blk >> 6, s = blk & 63;       // 32 b-points per s-chunk
    __shared__ float FT[64][37];                // F^T[j][k]
    __shared__ float g[96];                     // b-geometry [32][3]
    __shared__ float gxp[2048], gyp[2048], gzp[2048];  // z geometry, swizzled p'=(p&7)*256+(p>>3)
    const float* fz = feat + ((size_t)z * NPTS + s * 32) * 64;
    const float* gz = geom + (size_t)z * NPTS * 3;
    {
      const int row = t >> 3, j0 = (t & 7) << 3;
      const float4 v0 = *(const float4*)&fz[row * 64 + j0];
      const float4 v1 = *(const float4*)&fz[row * 64 + j0 + 4];
      FT[j0 + 0][row] = v0.x; FT[j0 + 1][row] = v0.y;
      FT[j0 + 2][row] = v0.z; FT[j0 + 3][row] = v0.w;
      FT[j0 + 4][row] = v1.x; FT[j0 + 5][row] = v1.y;
      FT[j0 + 6][row] = v1.z; FT[j0 + 7][row] = v1.w;
    }
    if (t < 96) g[t] = gz[s * 96 + t];
    {  // stage geometry planes: thread reads 24 contiguous floats (8 points)
      float v[24];
#pragma unroll
      for (int i = 0; i < 6; ++i) *(float4*)&v[i * 4] = *(const float4*)&gz[t * 24 + i * 4];
#pragma unroll
      for (int i = 0; i < 8; ++i) {
        const int pp = i * 256 + t;             // swizzled slot (conflict-free)
        gxp[pp] = v[i * 3 + 0]; gyp[pp] = v[i * 3 + 1]; gzp[pp] = v[i * 3 + 2];
      }
    }
    __syncthreads();

    {  // ---- Bp build (R4 verbatim) ----
      const int w = t >> 6, L = t & 63;
      const int nn = L >> 2, k0 = (L & 3) * 8;
      const int j = w * 16 + nn;
      float f[8];
#pragma unroll
      for (int i = 0; i < 8; ++i) f[i] = FT[j][k0 + i];
      float gx[3][8];
#pragma unroll
      for (int x = 0; x < 3; ++x)
#pragma unroll
        for (int i = 0; i < 8; ++i) gx[x][i] = g[(k0 + i) * 3 + x];
      unsigned char* base = ws + BP_OFF + (size_t)z * 1048576 + (size_t)w * 65536 +
                            (size_t)s * 1024 + L * 16;
#pragma unroll
      for (int it = 0; it < 4; ++it) {          // x = it; frag qb = it*4 + w
        u32x4 pv;
#pragma unroll
        for (int p = 0; p < 4; ++p) {
          float f0 = f[2 * p], f1 = f[2 * p + 1];
          if (it < 3) { f0 *= gx[it][2 * p]; f1 *= gx[it][2 * p + 1]; }
          pv[p] = f2bf(f0) | (f2bf(f1) << 16);
        }
        *(u32x4*)(base + (size_t)it * 4 * 65536) = pv;
      }
    }

    {  // ---- mask bitwords: rows t*8..+8 vs b = s*32..+32 ----
      float ax[8], ay[8], az[8];
#pragma unroll
      for (int i = 0; i < 8; ++i) {
        const int pp = i * 256 + t;
        ax[i] = gxp[pp]; ay[i] = gyp[pp]; az[i] = gzp[pp];
      }
      unsigned bits[8] = {0, 0, 0, 0, 0, 0, 0, 0};
      for (int j = 0; j < 32; ++j) {
        const float bx = g[j * 3 + 0], by = g[j * 3 + 1], bz = g[j * 3 + 2];
#pragma unroll
        for (int i = 0; i < 8; ++i) {
          const float d0 = bx - ax[i], d1 = by - ay[i], d2 = bz - az[i];
          const float n2 = fmaf(d2, d2, fmaf(d1, d1, d0 * d0));
          bits[i] |= (n2 < 1.0f ? 1u : 0u) << j;
        }
      }
      unsigned int* mw = (unsigned int*)(ws + MW_OFF);
#pragma unroll
      for (int i = 0; i < 8; ++i) {
        const int r = t * 8 + i;
        mw[(((size_t)z * 32 + (r >> 6)) * 64 + s) * 64 + (r & 15) * 4 + ((r >> 4) & 3)] = bits[i];
      }
    }
  } else if (blk == 512) {   // W2F frags (R4 verbatim)
    for (int e = t; e < 1536; e += 256) {
      const int frag = e >> 6, lp = e & 63, nn = lp >> 2, qd = lp & 3;
      const int kb = frag >> 2, cb = frag & 3;
      u32x4 pv;
#pragma unroll
      for (int p = 0; p < 4; ++p) {
        const int k0 = kb * 32 + qd * 8 + 2 * p;
        const float v0 = Wk[(k0 >> 6) * 4096 + (cb * 16 + nn) * 64 + (k0 & 63)];
        const float v1 = Wk[((k0 + 1) >> 6) * 4096 + (cb * 16 + nn) * 64 + ((k0 + 1) & 63)];
        pv[p] = f2bf(v0) | (f2bf(v1) << 16);
      }
      *(u32x4*)(ws + W2F_OFF + (size_t)frag * 1024 + lp * 16) = pv;
    }
  } else {                   // WXF frags (R4 verbatim)
    for (int e = t; e < 1536; e += 256) {
      const int frag = e >> 6, lp = e & 63, nn = lp >> 2, qd = lp & 3;
      const int kb = frag / 12, cb = frag % 12, xi = cb * 16 + nn;
      u32x4 pv;
#pragma unroll
      for (int p = 0; p < 4; ++p) {
        const int k0 = kb * 32 + qd * 8 + 2 * p;
        const float v0 = Wk[(xi >> 6) * 4096 + (xi & 63) * 64 + k0];
        const float v1 = Wk[(xi >> 6) * 4096 + (xi & 63) * 64 + k0 + 1];
        pv[p] = f2bf(v0) | (f2bf(v1) << 16);
      }
      *(u32x4*)(ws + WXF_OFF + (size_t)frag * 1024 + lp * 16) = pv;
    }
  }
}

// ========== K2: zero-redundancy mask-GEMM + fused epilogue (atomic merge) ==========
// grid 512 = (z = bx&7, at = (bx>>3)&31, ch = bx>>8). 256 thr = 4 waves.
// Wave w: ALL 64 rows x cols 32w (block half ch*128..): qb = ch*8 + 2w + {0,1}.
// Masks from global bitwords (1 dwordx4/step). Zero barriers in K-loop.
__global__ __launch_bounds__(256, 2) void k2_gemm(const float* __restrict__ geom,
                                                  const unsigned char* __restrict__ ws,
                                                  float* __restrict__ out) {
  __shared__ __align__(16) unsigned short Ct[64 * 128];   // 16 KB, bf16 C-transpose

  const int t = threadIdx.x, lane = t & 63, w = t >> 6;   // w = 0..3
  const int quad = (lane >> 4) & 3, n = lane & 15;
  const int bx = blockIdx.x;
  const int z = bx & 7, at = (bx >> 3) & 31, ch = bx >> 8;
  const int a0 = at * 64;
  const int fragoff = n * 64 + quad * 16;
  const int qsh = quad * 8;

  const unsigned char* bpz = ws + BP_OFF + (size_t)z * 1048576 +
                             (size_t)(ch * 8 + 2 * w) * 65536;
  const unsigned char* mwz = ws + MW_OFF + ((size_t)z * 32 + at) * 16384;

  f32x4 acc[4][2];
#pragma unroll
  for (int rg = 0; rg < 4; ++rg)
#pragma unroll
    for (int cb = 0; cb < 2; ++cb)
#pragma unroll
      for (int r = 0; r < 4; ++r) acc[rg][cb][r] = 0.f;

  bf16x8 Bf[2][2];
  u32x4 Mf[2];
#pragma unroll
  for (int sl = 0; sl < 2; ++sl) {
#pragma unroll
    for (int cb = 0; cb < 2; ++cb)
      Bf[sl][cb] = *(const bf16x8*)(bpz + (size_t)cb * 65536 + (size_t)sl * 1024 + fragoff);
    Mf[sl] = *(const u32x4*)(mwz + sl * 256 + n * 16);
  }

#define KSTEP(S, SL)                                                           \
  {                                                                            \
    const u32x4 mw = Mf[SL];                                                   \
    _Pragma("unroll") for (int rg = 0; rg < 4; ++rg) {                         \
      const bf16x8 Af = unpack_mask((mw[rg] >> qsh) & 0xFFu);                  \
      _Pragma("unroll") for (int cb = 0; cb < 2; ++cb)                         \
        acc[rg][cb] = __builtin_amdgcn_mfma_f32_16x16x32_bf16(                 \
            Af, Bf[SL][cb], acc[rg][cb], 0, 0, 0);                             \
    }                                                                          \
    const int sp = (S) + 2 > 63 ? 63 : (S) + 2;                                \
    Mf[SL] = *(const u32x4*)(mwz + sp * 256 + n * 16);                         \
    _Pragma("unroll") for (int cb = 0; cb < 2; ++cb)                           \
      Bf[SL][cb] = *(const bf16x8*)(bpz + (size_t)cb * 65536 +                 \
                                    (size_t)sp * 1024 + fragoff);              \
  }

  for (int s2 = 0; s2 < 64; s2 += 2) {
    KSTEP(s2, 0)
    KSTEP(s2 + 1, 1)
  }
#undef KSTEP

  // ---- epilogue: acc -> bf16 Ct (16B-chunk XOR swizzle) ----
#pragma unroll
  for (int rg = 0; rg < 4; ++rg)
#pragma unroll
    for (int cb = 0; cb < 2; ++cb)
#pragma unroll
      for (int r = 0; r < 4; ++r) {
        const int row = rg * 16 + quad * 4 + r;            // C/D: row = quad*4+r
        const int col = w * 32 + cb * 16 + n;              // local q (0..127)
        Ct[row * 128 + ((((col >> 3) ^ (row & 15)) & 15) << 3) + (col & 7)] =
            (unsigned short)f2bf(acc[rg][cb][r]);
      }
  __syncthreads();

  // ---- weight GEMM on this block's q-half; atomic merge into out ----
  const int lm = 16 * w + n;
  bf16x8 Across[4];
#pragma unroll
  for (int kbl = 0; kbl < 4; ++kbl) {
    const int chunk = ((kbl * 4 + quad) ^ (lm & 15)) & 15;
    Across[kbl] = *(const bf16x8*)&Ct[lm * 128 + (chunk << 3)];
  }

  const unsigned char* w2f = ws + W2F_OFF;
  const unsigned char* wxf = ws + WXF_OFF;

  if (ch == 0) {
    f32x4 mn[4];
#pragma unroll
    for (int i = 0; i < 4; ++i)
#pragma unroll
      for (int r = 0; r < 4; ++r) mn[i][r] = 0.f;
#pragma unroll
    for (int kbl = 0; kbl < 4; ++kbl)                      // global kb = kbl
#pragma unroll
      for (int cb = 0; cb < 4; ++cb) {
        const bf16x8 Bfr = *(const bf16x8*)(w2f + (size_t)(kbl * 4 + cb) * 1024 + fragoff);
        mn[cb] = __builtin_amdgcn_mfma_f32_16x16x32_bf16(Across[kbl], Bfr, mn[cb], 0, 0, 0);
      }
#pragma unroll
    for (int r = 0; r < 4; ++r) {
      const int af = a0 + 16 * w + quad * 4 + r;
#pragma unroll
      for (int cb = 0; cb < 4; ++cb)
        atomicAdd(&out[((size_t)z * NPTS + af) * 64 + cb * 16 + n], mn[cb][r]);
    }
  } else {
    f32x4 mn[4], V[12];
#pragma unroll
    for (int i = 0; i < 4; ++i)
#pragma unroll
      for (int r = 0; r < 4; ++r) mn[i][r] = 0.f;
#pragma unroll
    for (int i = 0; i < 12; ++i)
#pragma unroll
      for (int r = 0; r < 4; ++r) V[i][r] = 0.f;
#pragma unroll
    for (int kbl = 0; kbl < 2; ++kbl)                      // global kb = 4+kbl
#pragma unroll
      for (int cb = 0; cb < 4; ++cb) {
        const bf16x8 Bfr = *(const bf16x8*)(w2f + (size_t)((4 + kbl) * 4 + cb) * 1024 + fragoff);
        mn[cb] = __builtin_amdgcn_mfma_f32_16x16x32_bf16(Across[kbl], Bfr, mn[cb], 0, 0, 0);
      }
#pragma unroll
    for (int kbl = 0; kbl < 2; ++kbl)                      // T0: Across[2],[3]
#pragma unroll
      for (int cb = 0; cb < 12; ++cb) {
        const bf16x8 Bfr = *(const bf16x8*)(wxf + (size_t)(kbl * 12 + cb) * 1024 + fragoff);
        V[cb] = __builtin_amdgcn_mfma_f32_16x16x32_bf16(Across[2 + kbl], Bfr, V[cb], 0, 0, 0);
      }
#pragma unroll
    for (int r = 0; r < 4; ++r) {
      const int af = a0 + 16 * w + quad * 4 + r;
      const float g0 = geom[((size_t)z * NPTS + af) * 3 + 0];
      const float g1 = geom[((size_t)z * NPTS + af) * 3 + 1];
      const float g2 = geom[((size_t)z * NPTS + af) * 3 + 2];
#pragma unroll
      for (int cb = 0; cb < 4; ++cb) {
        const float v = mn[cb][r] - g0 * V[cb][r] - g1 * V[cb + 4][r] - g2 * V[cb + 8][r];
        atomicAdd(&out[((size_t)z * NPTS + af) * 64 + cb * 16 + n], v);
      }
    }
  }
}

extern "C" void kernel_launch(void* const* d_in, const int* in_sizes, int n_in,
                              void* d_out, int out_size, void* d_ws, size_t ws_size,
                              hipStream_t stream) {
  const float* feat = (const float*)d_in[0];  // [8,2048,64]
  const float* geom = (const float*)d_in[1];  // [8,2048,3]
  const float* Wk   = (const float*)d_in[2];  // [3,64,64]
  float* out = (float*)d_out;                 // [8,2048,64] fp32
  unsigned char* ws = (unsigned char*)d_ws;   // ~12.4 MB used

  hipMemsetAsync(out, 0, (size_t)out_size * sizeof(float), stream);  // atomic-merge base
  k1_prep<<<dim3(514), 256, 0, stream>>>(feat, geom, Wk, ws);
  k2_gemm<<<dim3(512), 256, 0, stream>>>(geom, ws, out);
}

// Round 10
// 102.856 us; speedup vs baseline: 2.1722x; 1.0557x over previous
//
#include <hip/hip_runtime.h>
#include <stdint.h>

#define NPTS 2048

// ---- workspace layout (bytes) ----
// Bp fragment-ordered (R4-verified): [z][qb=16][s=64][frag 1KB]; frag slot L holds
// (q-col n=L>>2, k-range (L&3)*8..+8). Reader lane (quad,n) -> offset n*64+quad*16.
#define BP_OFF    0ULL
#define BP_BYTES  (8ULL * 16 * 64 * 1024)      // 8 MB
#define W2F_OFF   (BP_OFF + BP_BYTES)
#define W2F_BYTES (24ULL * 1024)               // frags kb0..5 x cb0..3
#define WXF_OFF   (W2F_OFF + W2F_BYTES)
#define WXF_BYTES (24ULL * 1024)               // frags kb0..1 x cb0..11
// Mask words: [z][at=32][kw=64][64 dwords]; dword n*4+rg = word for row rg*16+n.
#define MW_OFF    (WXF_OFF + WXF_BYTES)
#define MW_BYTES  (8ULL * 32 * 64 * 256)       // 4 MB  (total ~12.4 MB)

typedef __attribute__((ext_vector_type(8))) short bf16x8;
typedef __attribute__((ext_vector_type(4))) float f32x4;
typedef __attribute__((ext_vector_type(4))) unsigned int u32x4;

__device__ __forceinline__ unsigned f2bf(float f) {
  union { float f; unsigned u; } v; v.f = f;
  return (v.u + 0x7FFFu + ((v.u >> 16) & 1u)) >> 16;  // RNE
}

__device__ __forceinline__ bf16x8 pack8(const float4 a, const float4 b) {
  u32x4 r;
  r[0] = f2bf(a.x) | (f2bf(a.y) << 16);
  r[1] = f2bf(a.z) | (f2bf(a.w) << 16);
  r[2] = f2bf(b.x) | (f2bf(b.y) << 16);
  r[3] = f2bf(b.z) | (f2bf(b.w) << 16);
  union { u32x4 u; bf16x8 h; } c; c.u = r; return c.h;
}

// 8 mask bits -> 8 bf16 (1.0/0.0): bit-deposit mul + v_perm + mul. (R9-verified)
__device__ __forceinline__ bf16x8 unpack_mask(unsigned mq) {
  const unsigned dep0 = ((mq & 15u) * 0x204081u) & 0x01010101u;        // bits0-3 -> bytes
  const unsigned dep1 = (((mq >> 4) & 15u) * 0x204081u) & 0x01010101u; // bits4-7
  u32x4 aw;
  aw[0] = __builtin_amdgcn_perm(dep0, 0u, 0x0C050C04u) * 0x3F80u;
  aw[1] = __builtin_amdgcn_perm(dep0, 0u, 0x0C070C06u) * 0x3F80u;
  aw[2] = __builtin_amdgcn_perm(dep1, 0u, 0x0C050C04u) * 0x3F80u;
  aw[3] = __builtin_amdgcn_perm(dep1, 0u, 0x0C070C06u) * 0x3F80u;
  union { u32x4 u; bf16x8 h; } cv; cv.u = aw;
  return cv.h;
}

// ========== K1: Bp frags + weight frags + mask bitwords (R9 verbatim — verified) ==========
__global__ __launch_bounds__(256, 2) void k1_prep(const float* __restrict__ feat,
                                                  const float* __restrict__ geom,
                                                  const float* __restrict__ Wk,
                                                  unsigned char* __restrict__ ws) {
  const int blk = blockIdx.x, t = threadIdx.x;
  if (blk < 512) {
    const int z = blk >> 6, s = blk & 63;       // 32 b-points per s-chunk
    __shared__ float FT[64][37];                // F^T[j][k]
    __shared__ float g[96];                     // b-geometry [32][3]
    __shared__ float gxp[2048], gyp[2048], gzp[2048];  // z geometry, swizzled p'=(p&7)*256+(p>>3)
    const float* fz = feat + ((size_t)z * NPTS + s * 32) * 64;
    const float* gz = geom + (size_t)z * NPTS * 3;
    {
      const int row = t >> 3, j0 = (t & 7) << 3;
      const float4 v0 = *(const float4*)&fz[row * 64 + j0];
      const float4 v1 = *(const float4*)&fz[row * 64 + j0 + 4];
      FT[j0 + 0][row] = v0.x; FT[j0 + 1][row] = v0.y;
      FT[j0 + 2][row] = v0.z; FT[j0 + 3][row] = v0.w;
      FT[j0 + 4][row] = v1.x; FT[j0 + 5][row] = v1.y;
      FT[j0 + 6][row] = v1.z; FT[j0 + 7][row] = v1.w;
    }
    if (t < 96) g[t] = gz[s * 96 + t];
    {  // stage geometry planes: thread reads 24 contiguous floats (8 points)
      float v[24];
#pragma unroll
      for (int i = 0; i < 6; ++i) *(float4*)&v[i * 4] = *(const float4*)&gz[t * 24 + i * 4];
#pragma unroll
      for (int i = 0; i < 8; ++i) {
        const int pp = i * 256 + t;             // swizzled slot (conflict-free)
        gxp[pp] = v[i * 3 + 0]; gyp[pp] = v[i * 3 + 1]; gzp[pp] = v[i * 3 + 2];
      }
    }
    __syncthreads();

    {  // ---- Bp build (R4 verbatim) ----
      const int w = t >> 6, L = t & 63;
      const int nn = L >> 2, k0 = (L & 3) * 8;
      const int j = w * 16 + nn;
      float f[8];
#pragma unroll
      for (int i = 0; i < 8; ++i) f[i] = FT[j][k0 + i];
      float gx[3][8];
#pragma unroll
      for (int x = 0; x < 3; ++x)
#pragma unroll
        for (int i = 0; i < 8; ++i) gx[x][i] = g[(k0 + i) * 3 + x];
      unsigned char* base = ws + BP_OFF + (size_t)z * 1048576 + (size_t)w * 65536 +
                            (size_t)s * 1024 + L * 16;
#pragma unroll
      for (int it = 0; it < 4; ++it) {          // x = it; frag qb = it*4 + w
        u32x4 pv;
#pragma unroll
        for (int p = 0; p < 4; ++p) {
          float f0 = f[2 * p], f1 = f[2 * p + 1];
          if (it < 3) { f0 *= gx[it][2 * p]; f1 *= gx[it][2 * p + 1]; }
          pv[p] = f2bf(f0) | (f2bf(f1) << 16);
        }
        *(u32x4*)(base + (size_t)it * 4 * 65536) = pv;
      }
    }

    {  // ---- mask bitwords: rows t*8..+8 vs b = s*32..+32 ----
      float ax[8], ay[8], az[8];
#pragma unroll
      for (int i = 0; i < 8; ++i) {
        const int pp = i * 256 + t;
        ax[i] = gxp[pp]; ay[i] = gyp[pp]; az[i] = gzp[pp];
      }
      unsigned bits[8] = {0, 0, 0, 0, 0, 0, 0, 0};
      for (int j = 0; j < 32; ++j) {
        const float bx = g[j * 3 + 0], by = g[j * 3 + 1], bz = g[j * 3 + 2];
#pragma unroll
        for (int i = 0; i < 8; ++i) {
          const float d0 = bx - ax[i], d1 = by - ay[i], d2 = bz - az[i];
          const float n2 = fmaf(d2, d2, fmaf(d1, d1, d0 * d0));
          bits[i] |= (n2 < 1.0f ? 1u : 0u) << j;
        }
      }
      unsigned int* mw = (unsigned int*)(ws + MW_OFF);
#pragma unroll
      for (int i = 0; i < 8; ++i) {
        const int r = t * 8 + i;
        mw[(((size_t)z * 32 + (r >> 6)) * 64 + s) * 64 + (r & 15) * 4 + ((r >> 4) & 3)] = bits[i];
      }
    }
  } else if (blk == 512) {   // W2F frags
    for (int e = t; e < 1536; e += 256) {
      const int frag = e >> 6, lp = e & 63, nn = lp >> 2, qd = lp & 3;
      const int kb = frag >> 2, cb = frag & 3;
      u32x4 pv;
#pragma unroll
      for (int p = 0; p < 4; ++p) {
        const int k0 = kb * 32 + qd * 8 + 2 * p;
        const float v0 = Wk[(k0 >> 6) * 4096 + (cb * 16 + nn) * 64 + (k0 & 63)];
        const float v1 = Wk[((k0 + 1) >> 6) * 4096 + (cb * 16 + nn) * 64 + ((k0 + 1) & 63)];
        pv[p] = f2bf(v0) | (f2bf(v1) << 16);
      }
      *(u32x4*)(ws + W2F_OFF + (size_t)frag * 1024 + lp * 16) = pv;
    }
  } else {                   // WXF frags
    for (int e = t; e < 1536; e += 256) {
      const int frag = e >> 6, lp = e & 63, nn = lp >> 2, qd = lp & 3;
      const int kb = frag / 12, cb = frag % 12, xi = cb * 16 + nn;
      u32x4 pv;
#pragma unroll
      for (int p = 0; p < 4; ++p) {
        const int k0 = kb * 32 + qd * 8 + 2 * p;
        const float v0 = Wk[(xi >> 6) * 4096 + (xi & 63) * 64 + k0];
        const float v1 = Wk[(xi >> 6) * 4096 + (xi & 63) * 64 + k0 + 1];
        pv[p] = f2bf(v0) | (f2bf(v1) << 16);
      }
      *(u32x4*)(ws + WXF_OFF + (size_t)frag * 1024 + lp * 16) = pv;
    }
  }
}

// ========== K2: zero-redundancy mask-GEMM, no atomics ==========
// grid 256 = (z = bx&7, at = bx>>3). 512 thr = 8 waves.
// Wave w: ALL 64 rows x cols 32w..32w+31 (qb = 2w, 2w+1) -> one reader per B-frag.
// Masks via 1 dwordx4/step from k1's bitword table. Zero barriers in K-loop.
// Epilogue: R4-verified transpose + weight GEMM, direct stores.
__global__ __launch_bounds__(512, 2) void k2_gemm(const float* __restrict__ geom,
                                                  const unsigned char* __restrict__ ws,
                                                  float* __restrict__ out) {
  __shared__ __align__(16) float Ct[64 * 256];            // 64 KB

  const int t = threadIdx.x, lane = t & 63, w = t >> 6;   // w = 0..7
  const int quad = (lane >> 4) & 3, n = lane & 15;
  const int bx = blockIdx.x;
  const int z = bx & 7, at = bx >> 3, a0 = at * 64;
  const int fragoff = n * 64 + quad * 16;
  const int qsh = quad * 8;

  const unsigned char* bpz = ws + BP_OFF + (size_t)z * 1048576 + (size_t)(2 * w) * 65536;
  const unsigned char* mwz = ws + MW_OFF + ((size_t)z * 32 + at) * 16384;

  f32x4 acc[4][2];
#pragma unroll
  for (int rg = 0; rg < 4; ++rg)
#pragma unroll
    for (int cb = 0; cb < 2; ++cb)
#pragma unroll
      for (int r = 0; r < 4; ++r) acc[rg][cb][r] = 0.f;

  bf16x8 Bf[4][2];                              // 4-deep pipeline
  u32x4 Mf[4];
#pragma unroll
  for (int sl = 0; sl < 4; ++sl) {
#pragma unroll
    for (int cb = 0; cb < 2; ++cb)
      Bf[sl][cb] = *(const bf16x8*)(bpz + (size_t)cb * 65536 + (size_t)sl * 1024 + fragoff);
    Mf[sl] = *(const u32x4*)(mwz + sl * 256 + n * 16);
  }

#define KSTEP(S, SL)                                                           \
  {                                                                            \
    const u32x4 mw = Mf[SL];                                                   \
    _Pragma("unroll") for (int rg = 0; rg < 4; ++rg) {                         \
      const bf16x8 Af = unpack_mask((mw[rg] >> qsh) & 0xFFu);                  \
      _Pragma("unroll") for (int cb = 0; cb < 2; ++cb)                         \
        acc[rg][cb] = __builtin_amdgcn_mfma_f32_16x16x32_bf16(                 \
            Af, Bf[SL][cb], acc[rg][cb], 0, 0, 0);                             \
    }                                                                          \
    const int sp = (S) + 4 > 63 ? 63 : (S) + 4;                                \
    Mf[SL] = *(const u32x4*)(mwz + sp * 256 + n * 16);                         \
    _Pragma("unroll") for (int cb = 0; cb < 2; ++cb)                           \
      Bf[SL][cb] = *(const bf16x8*)(bpz + (size_t)cb * 65536 +                 \
                                    (size_t)sp * 1024 + fragoff);              \
  }

  for (int s4 = 0; s4 < 64; s4 += 4) {
    KSTEP(s4 + 0, 0) KSTEP(s4 + 1, 1) KSTEP(s4 + 2, 2) KSTEP(s4 + 3, 3)
  }
#undef KSTEP

  // ---- epilogue: acc -> Ct fp32 (R4 XOR swizzle), then weight GEMM on waves 0..3 ----
#pragma unroll
  for (int rg = 0; rg < 4; ++rg)
#pragma unroll
    for (int cb = 0; cb < 2; ++cb)
#pragma unroll
      for (int r = 0; r < 4; ++r) {
        const int row = rg * 16 + quad * 4 + r;            // C/D: row = quad*4+r
        const int col = 32 * w + cb * 16 + n;              // C/D: col = n
        Ct[row * 256 + (((col >> 2) ^ row) << 2) + (col & 3)] = acc[rg][cb][r];
      }
  __syncthreads();

  if (w < 4) {
    const int lm = 16 * w + n;                             // final-GEMM A row
    bf16x8 Across[8];
#pragma unroll
    for (int kb = 0; kb < 8; ++kb) {
      const int c0 = (kb * 8 + quad * 2) ^ lm;
      const int c1 = (kb * 8 + quad * 2 + 1) ^ lm;
      const float4 f0 = *(const float4*)&Ct[lm * 256 + c0 * 4];
      const float4 f1 = *(const float4*)&Ct[lm * 256 + c1 * 4];
      Across[kb] = pack8(f0, f1);
    }

    f32x4 mn[4], V[12];
#pragma unroll
    for (int i = 0; i < 4; ++i)
#pragma unroll
      for (int r = 0; r < 4; ++r) mn[i][r] = 0.f;
#pragma unroll
    for (int i = 0; i < 12; ++i)
#pragma unroll
      for (int r = 0; r < 4; ++r) V[i][r] = 0.f;

    const unsigned char* w2f = ws + W2F_OFF;
    const unsigned char* wxf = ws + WXF_OFF;
#pragma unroll
    for (int kb = 0; kb < 6; ++kb)
#pragma unroll
      for (int cb = 0; cb < 4; ++cb) {
        const bf16x8 Bfr = *(const bf16x8*)(w2f + (size_t)(kb * 4 + cb) * 1024 + fragoff);
        mn[cb] = __builtin_amdgcn_mfma_f32_16x16x32_bf16(Across[kb], Bfr, mn[cb], 0, 0, 0);
      }
#pragma unroll
    for (int kb = 0; kb < 2; ++kb)
#pragma unroll
      for (int cb = 0; cb < 12; ++cb) {
        const bf16x8 Bfr = *(const bf16x8*)(wxf + (size_t)(kb * 12 + cb) * 1024 + fragoff);
        V[cb] = __builtin_amdgcn_mfma_f32_16x16x32_bf16(Across[6 + kb], Bfr, V[cb], 0, 0, 0);
      }

#pragma unroll
    for (int r = 0; r < 4; ++r) {
      const int af = a0 + 16 * w + quad * 4 + r;           // C/D row = quad*4 + r
      const float g0 = geom[((size_t)z * NPTS + af) * 3 + 0];
      const float g1 = geom[((size_t)z * NPTS + af) * 3 + 1];
      const float g2 = geom[((size_t)z * NPTS + af) * 3 + 2];
#pragma unroll
      for (int cb = 0; cb < 4; ++cb) {
        const float v = mn[cb][r] - g0 * V[cb][r] - g1 * V[cb + 4][r] - g2 * V[cb + 8][r];
        out[((size_t)z * NPTS + af) * 64 + cb * 16 + n] = v;
      }
    }
  }
}

extern "C" void kernel_launch(void* const* d_in, const int* in_sizes, int n_in,
                              void* d_out, int out_size, void* d_ws, size_t ws_size,
                              hipStream_t stream) {
  const float* feat = (const float*)d_in[0];  // [8,2048,64]
  const float* geom = (const float*)d_in[1];  // [8,2048,3]
  const float* Wk   = (const float*)d_in[2];  // [3,64,64]
  float* out = (float*)d_out;                 // [8,2048,64] fp32
  unsigned char* ws = (unsigned char*)d_ws;   // ~12.4 MB used

  k1_prep<<<dim3(514), 256, 0, stream>>>(feat, geom, Wk, ws);
  k2_gemm<<<dim3(256), 512, 0, stream>>>(geom, ws, out);
}